// Round 3
// baseline (300.801 us; speedup 1.0000x reference)
//
#include <hip/hip_runtime.h>
#include <cstdint>
#include <cstddef>

// LSTM cell: B=4096, IN=1024, H=1024
//   ifgo = h @ Wh^T + bh + x @ Wx^T    [4096 x 4096]
//   i,f,g,o = split(ifgo); c' = sig(f)*c + sig(i)*tanh(g); h' = o*tanh(c')
//
// Pipeline (2 dispatches):
//   1. convert: fp32->bf16, 8 floats/thread (16B stores), K=2048 layout
//      (A_cat=[h|x], W_cat=[Wh|Wx]) with W rows permuted
//      p=((j>>4)<<6)|(gate<<4)|(j&15).
//   2. gemm: 256x256 tile, BK=64, 8 waves.  A operand loaded DIRECTLY from
//      global (L1-resident 32KB k-panel, 4x wave reuse) -- no LDS round-trip.
//      B staged in LDS (XOR swizzle, conflicts=0).  ONE barrier per K-tile:
//      per-wave lgkm(0)+vmcnt(0) drain only old loads, STAGE issued after
//      the barrier, next tile's a03/b01 fragments prefetched under q4's
//      register-only MFMA.  Fused fast-math LSTM gate epilogue.

#define NB   4096
#define KH   1024
#define KK   2048
#define ARR_ELEMS 4194304  // 4096*1024
#define NKT  32            // K tiles of 64

typedef __bf16 bf16x8 __attribute__((ext_vector_type(8)));
typedef float  f32x4  __attribute__((ext_vector_type(4)));

__device__ inline unsigned short f2bf(float f) {
    union { float f; unsigned int u; } v; v.f = f;
    unsigned int u = v.u;
    u += 0x7FFFu + ((u >> 16) & 1u);   // RNE
    return (unsigned short)(u >> 16);
}

__device__ inline float fsig(float v)  { return __builtin_amdgcn_rcpf(1.f + __expf(-v)); }
__device__ inline float ftanh(float v) { return 1.f - 2.f * __builtin_amdgcn_rcpf(1.f + __expf(2.f * v)); }

// ---------------------------------------------------------------- convert ---
__global__ void convert_kernel(const float* __restrict__ h, const float* __restrict__ x,
                               const float* __restrict__ Wh, const float* __restrict__ Wx,
                               unsigned short* __restrict__ A, unsigned short* __restrict__ W) {
    int idx = blockIdx.x * 256 + threadIdx.x;       // 0 .. 2M-1
    int arr = idx >> 19;
    int off = (idx & 0x7FFFF) << 3;
    const float* src = (arr == 0) ? h : (arr == 1) ? x : (arr == 2) ? Wh : Wx;
    float4 v0 = *(const float4*)(src + off);
    float4 v1 = *(const float4*)(src + off + 4);
    uint4 packed;
    packed.x = (unsigned int)f2bf(v0.x) | ((unsigned int)f2bf(v0.y) << 16);
    packed.y = (unsigned int)f2bf(v0.z) | ((unsigned int)f2bf(v0.w) << 16);
    packed.z = (unsigned int)f2bf(v1.x) | ((unsigned int)f2bf(v1.y) << 16);
    packed.w = (unsigned int)f2bf(v1.z) | ((unsigned int)f2bf(v1.w) << 16);

    int row = off >> 10;
    int col = off & 1023;
    unsigned short* dst;
    size_t dstOff;
    if (arr < 2) {                                  // A_cat: [h | x] per row
        dst = A;
        dstOff = (size_t)row * KK + (arr == 1 ? 1024 : 0) + col;
    } else {                                        // W_cat: permuted rows
        int g = row >> 10, j = row & 1023;
        int p = ((j >> 4) << 6) | (g << 4) | (j & 15);
        dst = W;
        dstOff = (size_t)p * KK + (arr == 3 ? 1024 : 0) + col;
    }
    *(uint4*)(dst + dstOff) = packed;
}

// ------------------------------------------------------------------- gemm ---
// 512 threads = 8 waves (2 M-halves x 4 N-quarters). Wave output 128x64.
//
// Per K-tile T (buf = T&1), steady state; on entry a03(T), b01(T) in regs:
//   READ_B b23(T)        (4x ds_read_b128, swizzled)
//   LOAD_A a47(T)        (8x global_load_dwordx4, L1/L2)
//   q1 = a03 x b01   q2 = a03 x b23   q3 = a47 x b01   (48 MFMA, counted waits)
//   lgkm(0) ; vmcnt(0)   <- drains only OLD loads (this tile's reads/stages)
//   s_barrier            <- simultaneously: buf dead (all waves' reads done)
//                          AND buf^1 published (all waves' STAGE(T+1) drained)
//   STAGE_B(T+2 -> buf)  (4x global_load_lds, write-after-read safe)
//   LOAD_A a03(T+1), READ_B b01(T+1) from buf^1   <- prefetch under q4
//   q4 = a47 x b23       (register-only, hides prefetch latency)
__global__ __launch_bounds__(512, 2) void gemm_kernel(const unsigned short* __restrict__ A,
                            const unsigned short* __restrict__ W,
                            const float* __restrict__ bh,
                            const float* __restrict__ c,
                            float* __restrict__ out) {
    __shared__ __align__(16) unsigned short Bs[2 * 16384];   // 64 KiB (B only)

    const int tid  = threadIdx.x;
    const int wave = tid >> 6;
    const int lane = tid & 63;

    // T1: 256 blocks, 8 XCDs -> contiguous 32-tile chunks per XCD
    const int bid   = (int)blockIdx.x;
    const int swz   = (bid & 7) * 32 + (bid >> 3);
    const int tileM = swz >> 4;        // 0..15
    const int tileN = swz & 15;        // 0..15

    const int wr  = wave >> 2;         // 0..1  M half
    const int wc  = wave & 3;          // 0..3  N quarter
    const int fr  = lane & 15;
    const int fkE = (lane >> 4) * 8;   // fragment k-offset in elems {0,8,16,24}
    const int fk2 = fkE * 2;           // ... in bytes

    // ---- A: direct per-lane global pointers, one per 16-row fragment ------
    const int rowBase = tileM * 256 + wr * 128;
    const unsigned short* pA[8];
    #pragma unroll
    for (int i = 0; i < 8; ++i)
        pA[i] = A + (size_t)(rowBase + i * 16 + fr) * KK + fkE;

    // ---- B staging: per-thread pre-swizzled global source pointers --------
    const unsigned short* pb[4];
    #pragma unroll
    for (int i = 0; i < 4; ++i) {
        const int P   = (i * 512 + tid) * 16;
        const int L   = P ^ (((P >> 7) & 7) << 4);
        const int row = L >> 7;
        const int kk  = (L & 127) >> 1;
        pb[i] = W + (size_t)(tileN * 256 + row) * KK + kk;
    }

    // ---- B compute-side swizzled LDS byte offsets -------------------------
    const int swzm = (fr & 7) << 4;
    int offB[4];
    #pragma unroll
    for (int j = 0; j < 4; ++j)
        offB[j] = (wc * 64 + j * 16 + fr) * 128 + (fk2 ^ swzm);
    // second K=32 panel (s=1): offset ^ 64

    f32x4 acc[8][4] = {};
    bf16x8 a03[4][2], a47[4][2], b01[2][2], b23[2][2];

#define STAGE(KT, BUF) do { \
    const size_t _ko = (size_t)(KT) * 64; \
    _Pragma("unroll") \
    for (int _i = 0; _i < 4; ++_i) { \
        __builtin_amdgcn_global_load_lds( \
            (const __attribute__((address_space(1))) void*)(pb[_i] + _ko), \
            (__attribute__((address_space(3))) void*)(Bs + (BUF) * 16384 + _i * 4096 + wave * 512), 16, 0, 0); \
    } \
} while (0)

#define LOAD_A(dst, ibase, T) do { \
    _Pragma("unroll") \
    for (int _i = 0; _i < 4; ++_i) { \
        dst[_i][0] = *(const bf16x8*)(pA[(ibase) + _i] + (T) * 64); \
        dst[_i][1] = *(const bf16x8*)(pA[(ibase) + _i] + (T) * 64 + 32); \
    } \
} while (0)

#define READ_B(dst, jbase, BsB) do { \
    _Pragma("unroll") \
    for (int _j = 0; _j < 2; ++_j) { \
        dst[_j][0] = *(const bf16x8*)((BsB) + offB[(jbase) + _j]); \
        dst[_j][1] = *(const bf16x8*)((BsB) + (offB[(jbase) + _j] ^ 64)); \
    } \
} while (0)

#define MFMAQ(af, bf, IB, JB) do { \
    __builtin_amdgcn_s_setprio(1); \
    _Pragma("unroll") \
    for (int _i = 0; _i < 4; ++_i) \
        _Pragma("unroll") \
        for (int _j = 0; _j < 2; ++_j) \
            _Pragma("unroll") \
            for (int _s = 0; _s < 2; ++_s) \
                acc[(IB) + _i][(JB) + _j] = __builtin_amdgcn_mfma_f32_16x16x32_bf16( \
                    af[_i][_s], bf[_j][_s], acc[(IB) + _i][(JB) + _j], 0, 0, 0); \
    __builtin_amdgcn_s_setprio(0); \
} while (0)

// Hazard invariants (single barrier per tile):
//  I1 read-validity: b01(T) read in T-1's post-bar region; STAGE(T->buf) was
//     drained by every wave's own vmcnt(0) at T-1's clump, published by T-1's
//     barrier.  b23(T) read after the same barrier.
//  I2 write-after-read: STAGE(T+2->buf) issued after T's barrier; every
//     wave's reads of buf (b23 this tile, b01 last region) completed before
//     its own lgkm(0) pre-barrier.
//  I3 no new-load drain: vmcnt(0) pre-barrier drains only loads issued
//     >= 1 tile ago (a47(T) is consumed by q3's own counted wait anyway);
//     STAGE(T+2) is issued after the barrier.
#define TILEBODY(T, BUF) do { \
    const char* BsB = (const char*)Bs + (BUF) * 32768; \
    const char* BsN = (const char*)Bs + (((BUF) ^ 1)) * 32768; \
    READ_B(b23, 2, BsB); \
    LOAD_A(a47, 4, T); \
    MFMAQ(a03, b01, 0, 0); \
    MFMAQ(a03, b23, 0, 2); \
    MFMAQ(a47, b01, 4, 0); \
    asm volatile("s_waitcnt lgkmcnt(0)" ::: "memory"); \
    asm volatile("s_waitcnt vmcnt(0)" ::: "memory"); \
    asm volatile("s_barrier" ::: "memory"); \
    { \
        const int _kt2 = ((T) + 2 <= NKT - 1) ? ((T) + 2) : (NKT - 1); \
        const int _kt1 = ((T) + 1 <= NKT - 1) ? ((T) + 1) : (NKT - 1); \
        STAGE(_kt2, BUF);          /* tail-clamped: writes only dead bufs */ \
        LOAD_A(a03, 0, _kt1); \
        READ_B(b01, 0, BsN); \
    } \
    MFMAQ(a47, b23, 4, 2); \
} while (0)

    // prologue: B(0),B(1) in flight; wait B(0); publish; prefetch tile 0 frags
    STAGE(0, 0);
    STAGE(1, 1);
    asm volatile("s_waitcnt vmcnt(4)" ::: "memory");
    asm volatile("s_barrier" ::: "memory");
    LOAD_A(a03, 0, 0);
    READ_B(b01, 0, (const char*)Bs);

    for (int tt = 0; tt < NKT; tt += 2) {
        TILEBODY(tt, 0);
        TILEBODY(tt + 1, 1);
    }
#undef TILEBODY
#undef MFMAQ
#undef READ_B
#undef LOAD_A
#undef STAGE

    // ---- fused LSTM gate epilogue -----------------------------------------
    // acc[i][g][r]: row = tileM*256 + wr*128 + i*16 + (lane>>4)*4 + r,
    // gate g, logical j = (tileN*4+wc)*16 + (lane&15)
    const int j = ((tileN * 4 + wc) << 4) | fr;
    const float bi  = bh[j];
    const float bff = bh[j + 1024];
    const float bg  = bh[j + 2048];
    const float bo  = bh[j + 3072];

    const int row0 = tileM * 256 + wr * 128 + (lane >> 4) * 4;

    float cv[8][4];
    #pragma unroll
    for (int i = 0; i < 8; ++i)
        #pragma unroll
        for (int r = 0; r < 4; ++r)
            cv[i][r] = c[(size_t)(row0 + i * 16 + r) * KH + j];

    #pragma unroll
    for (int i = 0; i < 8; ++i) {
        #pragma unroll
        for (int r = 0; r < 4; ++r) {
            const size_t idx = (size_t)(row0 + i * 16 + r) * KH + j;
            float iv = fsig(acc[i][0][r] + bi);
            float fv = fsig(acc[i][1][r] + bff);
            float gv = ftanh(acc[i][2][r] + bg);
            float ov = fsig(acc[i][3][r] + bo);
            float cn = fv * cv[i][r] + iv * gv;
            float hn = ov * ftanh(cn);
            out[idx] = hn;
            out[(size_t)ARR_ELEMS + idx] = cn;
        }
    }
}

// ----------------------------------------------------------------- launch ---
extern "C" void kernel_launch(void* const* d_in, const int* in_sizes, int n_in,
                              void* d_out, int out_size, void* d_ws, size_t ws_size,
                              hipStream_t stream) {
    const float* x  = (const float*)d_in[0];
    const float* h  = (const float*)d_in[1];
    const float* c  = (const float*)d_in[2];
    const float* Wh = (const float*)d_in[3];
    const float* bh = (const float*)d_in[4];
    const float* Wx = (const float*)d_in[5];
    float* out = (float*)d_out;

    unsigned short* ws   = (unsigned short*)d_ws;
    unsigned short* Acat = ws;
    unsigned short* Wcat = ws + 2 * (size_t)ARR_ELEMS;

    convert_kernel<<<8192, 256, 0, stream>>>(h, x, Wh, Wx, Acat, Wcat);
    gemm_kernel<<<256, 512, 0, stream>>>(Acat, Wcat, bh, c, out);
}

// Round 4
// 201.299 us; speedup vs baseline: 1.4943x; 1.4943x over previous
//
#include <hip/hip_runtime.h>
#include <cstdint>
#include <cstddef>

// LSTM cell: B=4096, IN=1024, H=1024
//   ifgo = h @ Wh^T + bh + x @ Wx^T    [4096 x 4096]
//   i,f,g,o = split(ifgo); c' = sig(f)*c + sig(i)*tanh(g); h' = o*tanh(c')
//
// Pipeline (2 dispatches):
//   1. convert: fp32->bf16, 8 floats/thread (16B stores), K=2048 layout
//      (A_cat=[h|x], W_cat=[Wh|Wx]) with W rows permuted
//      p=((j>>4)<<6)|(gate<<4)|(j&15).   (identical to round-2)
//   2. gemm: 128x128 tile, BK=64, 4 waves, 64 KiB LDS -> 2 BLOCKS/CU.
//      Cross-block overlap (m114: independent blocks co-schedule MFMA and
//      LDS pipes) replaces fragile intra-block pipelining.  XOR-swizzled
//      LDS (conflicts=0), gload_lds staging, counted-vmcnt 2-barrier clump
//      (r2-proven race-free), XCD swizzle, NO setprio, low reg pressure.
//      Fused fast-math LSTM gate epilogue (r0-verified 128^2 mapping).

#define NB   4096
#define KH   1024
#define KK   2048
#define ARR_ELEMS 4194304  // 4096*1024
#define NKT  32            // K tiles of 64

typedef __bf16 bf16x8 __attribute__((ext_vector_type(8)));
typedef float  f32x4  __attribute__((ext_vector_type(4)));

__device__ inline unsigned short f2bf(float f) {
    union { float f; unsigned int u; } v; v.f = f;
    unsigned int u = v.u;
    u += 0x7FFFu + ((u >> 16) & 1u);   // RNE
    return (unsigned short)(u >> 16);
}

__device__ inline float fsig(float v)  { return __builtin_amdgcn_rcpf(1.f + __expf(-v)); }
__device__ inline float ftanh(float v) { return 1.f - 2.f * __builtin_amdgcn_rcpf(1.f + __expf(2.f * v)); }

// ---------------------------------------------------------------- convert ---
__global__ void convert_kernel(const float* __restrict__ h, const float* __restrict__ x,
                               const float* __restrict__ Wh, const float* __restrict__ Wx,
                               unsigned short* __restrict__ A, unsigned short* __restrict__ W) {
    int idx = blockIdx.x * 256 + threadIdx.x;       // 0 .. 2M-1
    int arr = idx >> 19;
    int off = (idx & 0x7FFFF) << 3;
    const float* src = (arr == 0) ? h : (arr == 1) ? x : (arr == 2) ? Wh : Wx;
    float4 v0 = *(const float4*)(src + off);
    float4 v1 = *(const float4*)(src + off + 4);
    uint4 packed;
    packed.x = (unsigned int)f2bf(v0.x) | ((unsigned int)f2bf(v0.y) << 16);
    packed.y = (unsigned int)f2bf(v0.z) | ((unsigned int)f2bf(v0.w) << 16);
    packed.z = (unsigned int)f2bf(v1.x) | ((unsigned int)f2bf(v1.y) << 16);
    packed.w = (unsigned int)f2bf(v1.z) | ((unsigned int)f2bf(v1.w) << 16);

    int row = off >> 10;
    int col = off & 1023;
    unsigned short* dst;
    size_t dstOff;
    if (arr < 2) {                                  // A_cat: [h | x] per row
        dst = A;
        dstOff = (size_t)row * KK + (arr == 1 ? 1024 : 0) + col;
    } else {                                        // W_cat: permuted rows
        int g = row >> 10, j = row & 1023;
        int p = ((j >> 4) << 6) | (g << 4) | (j & 15);
        dst = W;
        dstOff = (size_t)p * KK + (arr == 3 ? 1024 : 0) + col;
    }
    *(uint4*)(dst + dstOff) = packed;
}

// ------------------------------------------------------------------- gemm ---
// 256 threads = 4 waves (2M x 2N). Wave output 64x64 (acc[4][4]).
// LDS: double-buffered K-tiles, [128 rows][64 k] bf16 per matrix per buffer,
// XOR swizzle phys_byte = row*128 + (kbyte ^ ((row&7)<<4)); staging keeps LDS
// linear (global_load_lds) and pre-swizzles the per-lane GLOBAL address.
//
// Per K-tile T (buf = T&1):
//   read a[0..3], b[0..3] (16x ds_read_b128, swizzled; compiler counted lgkm)
//   32x MFMA 16x16x32
//   lgkm(0) ; barrier          <- all waves done reading buf
//   STAGE(T+2 -> buf)          <- 8x global_load_lds, write-after-read safe
//   vmcnt(8) ; barrier         <- tile T+1 (other buf, issued last tile) landed
__global__ __launch_bounds__(256, 2) void gemm_kernel(const unsigned short* __restrict__ A,
                            const unsigned short* __restrict__ W,
                            const float* __restrict__ bh,
                            const float* __restrict__ c,
                            float* __restrict__ out) {
    __shared__ __align__(16) unsigned short As[2 * 8192];   // 32 KiB
    __shared__ __align__(16) unsigned short Bs[2 * 8192];   // 32 KiB

    const int tid  = threadIdx.x;
    const int wave = tid >> 6;
    const int lane = tid & 63;

    // T1: 1024 blocks, 8 XCDs -> 128 contiguous tile-ids per XCD
    const int bid   = (int)blockIdx.x;
    const int swz   = (bid & 7) * 128 + (bid >> 3);
    const int tileM = swz >> 5;        // 0..31
    const int tileN = swz & 31;        // 0..31

    const int mBase = (wave >> 1) * 64;
    const int nBase = (wave & 1) * 64;
    const int fr  = lane & 15;
    const int fk2 = ((lane >> 4) << 4);   // fragment byte k-offset {0,16,32,48}

    // ---- staging: per-thread pre-swizzled global source pointers ----------
    // chunk c = i*256 + tid occupies LDS phys bytes [c*16, c*16+16) of the
    // 16KB panel; logical byte L = P ^ (((P>>7)&7)<<4) -> (row, k).
    const unsigned short* pa[4];
    const unsigned short* pb[4];
    #pragma unroll
    for (int i = 0; i < 4; ++i) {
        const int P   = (i * 256 + tid) * 16;
        const int L   = P ^ (((P >> 7) & 7) << 4);
        const int row = L >> 7;            // 0..127
        const int kk  = (L & 127) >> 1;    // elem 0..63
        pa[i] = A + (size_t)(tileM * 128 + row) * KK + kk;
        pb[i] = W + (size_t)(tileN * 128 + row) * KK + kk;
    }

    // ---- compute-side swizzled LDS byte offsets ---------------------------
    const int swzm = (fr & 7) << 4;
    int offA[4], offB[4];
    #pragma unroll
    for (int i = 0; i < 4; ++i) {
        offA[i] = (mBase + i * 16 + fr) * 128 + (fk2 ^ swzm);
        offB[i] = (nBase + i * 16 + fr) * 128 + (fk2 ^ swzm);
    }
    // second K=32 panel: offset ^ 64 (XOR commutes with the swizzle bits)

    f32x4 acc[4][4] = {};

#define STAGE(KT, BUF) do { \
    const size_t _ko = (size_t)(KT) * 64; \
    _Pragma("unroll") \
    for (int _i = 0; _i < 4; ++_i) { \
        __builtin_amdgcn_global_load_lds( \
            (const __attribute__((address_space(1))) void*)(pa[_i] + _ko), \
            (__attribute__((address_space(3))) void*)(As + (BUF) * 8192 + _i * 2048 + wave * 512), 16, 0, 0); \
        __builtin_amdgcn_global_load_lds( \
            (const __attribute__((address_space(1))) void*)(pb[_i] + _ko), \
            (__attribute__((address_space(3))) void*)(Bs + (BUF) * 8192 + _i * 2048 + wave * 512), 16, 0, 0); \
    } \
} while (0)

// Hazard invariants (unchanged from r2, halved geometry):
//  - tile T's data was confirmed landed by tile T-1's vmcnt(8)+barrier
//  - lgkm(0)+barrier after the reads -> buf dead for every wave
//  - STAGE(T+2->buf) issued after that barrier (write-after-read safe)
//  - vmcnt(8) leaves only the 8 just-issued loads outstanding -> the 8 loads
//    of tile T+1 (issued one tile ago) have landed; barrier publishes them
#define TILEBODY(T, BUF) do { \
    const char* AsB = (const char*)As + (BUF) * 16384; \
    const char* BsB = (const char*)Bs + (BUF) * 16384; \
    bf16x8 a[4][2], b[4][2]; \
    _Pragma("unroll") \
    for (int i = 0; i < 4; ++i) { \
        a[i][0] = *(const bf16x8*)(AsB + offA[i]); \
        a[i][1] = *(const bf16x8*)(AsB + (offA[i] ^ 64)); \
        b[i][0] = *(const bf16x8*)(BsB + offB[i]); \
        b[i][1] = *(const bf16x8*)(BsB + (offB[i] ^ 64)); \
    } \
    _Pragma("unroll") \
    for (int i = 0; i < 4; ++i) \
        _Pragma("unroll") \
        for (int j = 0; j < 4; ++j) \
            _Pragma("unroll") \
            for (int s = 0; s < 2; ++s) \
                acc[i][j] = __builtin_amdgcn_mfma_f32_16x16x32_bf16( \
                    a[i][s], b[j][s], acc[i][j], 0, 0, 0); \
    asm volatile("s_waitcnt lgkmcnt(0)" ::: "memory"); \
    asm volatile("s_barrier" ::: "memory"); \
    { \
        const int _kt = ((T) + 2 <= NKT - 1) ? ((T) + 2) : (NKT - 1); \
        STAGE(_kt, BUF);   /* tail-clamped: writes target only dead buffers */ \
    } \
    asm volatile("s_waitcnt vmcnt(8)" ::: "memory"); \
    asm volatile("s_barrier" ::: "memory"); \
} while (0)

    // prologue: tiles 0,1 in flight; wait until tile 0's 8 loads landed
    STAGE(0, 0);
    STAGE(1, 1);
    asm volatile("s_waitcnt vmcnt(8)" ::: "memory");
    asm volatile("s_barrier" ::: "memory");

    for (int tt = 0; tt < NKT; tt += 2) {
        TILEBODY(tt, 0);
        TILEBODY(tt + 1, 1);
    }
#undef TILEBODY
#undef STAGE

    // ---- fused LSTM gate epilogue (r0-verified 128^2 mapping) -------------
    // acc[i][g][r]: row = tileM*128 + mBase + i*16 + (lane>>4)*4 + r,
    // gate g, logical j = (tileN*2 + (wave&1))*16 + (lane&15)
    const int j = ((tileN * 2 + (wave & 1)) << 4) | fr;
    const float bi  = bh[j];
    const float bff = bh[j + 1024];
    const float bg  = bh[j + 2048];
    const float bo  = bh[j + 3072];

    const int row0 = tileM * 128 + mBase + (lane >> 4) * 4;

    float cv[4][4];
    #pragma unroll
    for (int i = 0; i < 4; ++i)
        #pragma unroll
        for (int r = 0; r < 4; ++r)
            cv[i][r] = c[(size_t)(row0 + i * 16 + r) * KH + j];

    #pragma unroll
    for (int i = 0; i < 4; ++i) {
        #pragma unroll
        for (int r = 0; r < 4; ++r) {
            const size_t idx = (size_t)(row0 + i * 16 + r) * KH + j;
            float iv = fsig(acc[i][0][r] + bi);
            float fv = fsig(acc[i][1][r] + bff);
            float gv = ftanh(acc[i][2][r] + bg);
            float ov = fsig(acc[i][3][r] + bo);
            float cn = fv * cv[i][r] + iv * gv;
            float hn = ov * ftanh(cn);
            out[idx] = hn;
            out[(size_t)ARR_ELEMS + idx] = cn;
        }
    }
}

// ----------------------------------------------------------------- launch ---
extern "C" void kernel_launch(void* const* d_in, const int* in_sizes, int n_in,
                              void* d_out, int out_size, void* d_ws, size_t ws_size,
                              hipStream_t stream) {
    const float* x  = (const float*)d_in[0];
    const float* h  = (const float*)d_in[1];
    const float* c  = (const float*)d_in[2];
    const float* Wh = (const float*)d_in[3];
    const float* bh = (const float*)d_in[4];
    const float* Wx = (const float*)d_in[5];
    float* out = (float*)d_out;

    unsigned short* ws   = (unsigned short*)d_ws;
    unsigned short* Acat = ws;
    unsigned short* Wcat = ws + 2 * (size_t)ARR_ELEMS;

    convert_kernel<<<8192, 256, 0, stream>>>(h, x, Wh, Wx, Acat, Wcat);
    dim3 grid(1024);
    gemm_kernel<<<grid, 256, 0, stream>>>(Acat, Wcat, bh, c, out);
}